// Round 11
// baseline (173.866 us; speedup 1.0000x reference)
//
#include <hip/hip_runtime.h>
#include <hip/hip_fp16.h>
#include <math.h>

#define NN 100000
#define NE 1600000
#define FIN 50
#define FP 52                         // padded FIN (multiple of 4, rows 16B-aligned)
#define NC 16
#define TILE_NODES 64                 // lin tile (2 nodes per thread)

#define NPB 256                       // nodes per bucket
#define NB  ((NN + NPB - 1) / NPB)    // 391 buckets
#define CAP 4608                      // slots per bucket region (mean 4092 + ~8 sigma)
#define NBLK_PART 256
#define EPB ((NE + NBLK_PART - 1) / NBLK_PART)   // 6250 edges / partition block
#define NBLK_LIN 768
#define NTILES ((NN + TILE_NODES - 1) / TILE_NODES)   // 1563

// ---------------------------------------------------------------------------
// Fused front-end.
// Place role (blocks [0,NBLK_PART)): R8-proven simple chunked placement —
// LDS hist -> one global cursor atomic per (block,bucket) -> chunked stores.
// Lin role (blocks [NBLK_PART,+NBLK_LIN)): y_l = x@W_l^T (f16) and
// self = x@W_r^T (f32). All LDS reads are float4 (ds_read_b128) on padded
// rows; 2 nodes x 4 (class,mat) accumulators per thread. Static smem kept at
// 20 KB so both roles can run 8 blocks/CU (R10's 44.5KB alloc throttled lin).
// ---------------------------------------------------------------------------
__global__ __launch_bounds__(256) void fused_front(
    const float* __restrict__ x,
    const float* __restrict__ W_l,
    const float* __restrict__ W_r,
    const int* __restrict__ ei,       // [2, NE]
    int* __restrict__ gcur_s,         // [NB*16] cursors (zeroed)
    unsigned int* __restrict__ buf,   // [NB*CAP]
    __half2* __restrict__ y_l,        // [NN*8]
    float* __restrict__ self_out)     // [NN*NC]
{
    __shared__ __align__(16) char smem[2 * NC * FP * 4 + TILE_NODES * FP * 4]; // 19968 B
    const int tid = threadIdx.x;

    if (blockIdx.x < NBLK_PART) {
        // ---- place role (R8 form) ----
        int* h   = (int*)smem;        // [NB]
        int* cur = h + NB;            // [NB]
        for (int i = tid; i < NB; i += 256) h[i] = 0;
        __syncthreads();
        int e0 = blockIdx.x * EPB;
        int e1 = min(e0 + EPB, NE);
        for (int e = e0 + tid; e < e1; e += 256)
            atomicAdd(&h[ei[NE + e] >> 8], 1);
        __syncthreads();
        for (int b = tid; b < NB; b += 256)
            cur[b] = h[b] ? atomicAdd(&gcur_s[b * 16], h[b]) : 0;
        __syncthreads();
        for (int e = e0 + tid; e < e1; e += 256) {
            int s = ei[e];
            int t = ei[NE + e];
            int b = t >> 8;
            int pos = atomicAdd(&cur[b], 1);
            if (pos < CAP)
                buf[(size_t)b * CAP + pos] = (unsigned)s | ((unsigned)(t & 255) << 17);
        }
    } else {
        // ---- lin role ----
        float* sWl = (float*)smem;            // [NC*FP]
        float* sWr = sWl + NC * FP;           // [NC*FP]
        float* sx  = sWr + NC * FP;           // [TILE_NODES*FP]

        for (int i = tid; i < NC * FP; i += 256) {
            int r = i / FP, c = i % FP;
            sWl[i] = (c < FIN) ? W_l[r * FIN + c] : 0.0f;
            sWr[i] = (c < FIN) ? W_r[r * FIN + c] : 0.0f;
        }

        const int bidx = blockIdx.x - NBLK_PART;
        const int lane = tid & 63;
        const int wv   = tid >> 6;
        const int ln = tid >> 3;          // 0..31
        const int cp = tid & 7;           // class pair

        const float4* w0 = (const float4*)(sWl + (2 * cp) * FP);
        const float4* w1 = (const float4*)(sWl + (2 * cp + 1) * FP);
        const float4* u0 = (const float4*)(sWr + (2 * cp) * FP);
        const float4* u1 = (const float4*)(sWr + (2 * cp + 1) * FP);
        const float4* xa = (const float4*)(sx + ln * FP);
        const float4* xb = (const float4*)(sx + (ln + 32) * FP);

        for (int tile = bidx; tile < NTILES; tile += NBLK_LIN) {
            __syncthreads();   // guards W fill (first iter) and sx reuse (later)
            const int node0 = tile * TILE_NODES;
            // stage 64 rows, one wave per row, zero-padded cols 50..51
            for (int r = wv; r < TILE_NODES; r += 4) {
                int n = node0 + r;
                float v = 0.0f;
                if (lane < FIN && n < NN) v = x[n * FIN + lane];
                if (lane < FP) sx[r * FP + lane] = v;
            }
            __syncthreads();

            float aA0 = 0.f, aA1 = 0.f, rA0 = 0.f, rA1 = 0.f;
            float aB0 = 0.f, aB1 = 0.f, rB0 = 0.f, rB1 = 0.f;
#pragma unroll
            for (int k = 0; k < FP / 4; ++k) {
                float4 va = xa[k], vb = xb[k];
                float4 p0 = w0[k], p1 = w1[k], q0 = u0[k], q1 = u1[k];
                aA0 = fmaf(va.x, p0.x, fmaf(va.y, p0.y, fmaf(va.z, p0.z, fmaf(va.w, p0.w, aA0))));
                aA1 = fmaf(va.x, p1.x, fmaf(va.y, p1.y, fmaf(va.z, p1.z, fmaf(va.w, p1.w, aA1))));
                rA0 = fmaf(va.x, q0.x, fmaf(va.y, q0.y, fmaf(va.z, q0.z, fmaf(va.w, q0.w, rA0))));
                rA1 = fmaf(va.x, q1.x, fmaf(va.y, q1.y, fmaf(va.z, q1.z, fmaf(va.w, q1.w, rA1))));
                aB0 = fmaf(vb.x, p0.x, fmaf(vb.y, p0.y, fmaf(vb.z, p0.z, fmaf(vb.w, p0.w, aB0))));
                aB1 = fmaf(vb.x, p1.x, fmaf(vb.y, p1.y, fmaf(vb.z, p1.z, fmaf(vb.w, p1.w, aB1))));
                rB0 = fmaf(vb.x, q0.x, fmaf(vb.y, q0.y, fmaf(vb.z, q0.z, fmaf(vb.w, q0.w, rB0))));
                rB1 = fmaf(vb.x, q1.x, fmaf(vb.y, q1.y, fmaf(vb.z, q1.z, fmaf(vb.w, q1.w, rB1))));
            }

            const int nA = node0 + ln;
            const int nB = nA + 32;
            if (nA < NN) {
                y_l[nA * 8 + cp] = __floats2half2_rn(aA0, aA1);
                ((float2*)self_out)[nA * 8 + cp] = make_float2(rA0, rA1);
            }
            if (nB < NN) {
                y_l[nB * 8 + cp] = __floats2half2_rn(aB0, aB1);
                ((float2*)self_out)[nB * 8 + cp] = make_float2(rB0, rB1);
            }
        }
    }
}

// ---------------------------------------------------------------------------
// Aggregation: one 1024-thread block per bucket (256 nodes). In-LDS counting
// sort (int atomics only), 256-wide scan, contention-free register
// segment-reduce (tid = tl*4+q), fused mean/bias/self/log_softmax epilogue.
// (R8-proven structure, unchanged.)
// ---------------------------------------------------------------------------
__global__ __launch_bounds__(1024) void agg_kernel(
    const int* __restrict__ gcur_s,
    const unsigned int* __restrict__ buf,
    const uint2* __restrict__ y2,     // y_l as uint2[NN*4]
    const float* __restrict__ b_l,
    float* __restrict__ logp,
    float* __restrict__ outv)         // self (f32) on entry, final out on exit
{
    __shared__ unsigned slist[CAP];   // 18.4 KB
    __shared__ int lcnt[NPB];
    __shared__ int scur[NPB];
    __shared__ int sstart[NPB];
    __shared__ int wsum[4];
    __shared__ float sb[NC];

    const int tid = threadIdx.x;
    if (tid < NPB) lcnt[tid] = 0;
    if (tid < NC) sb[tid] = b_l[tid];
    __syncthreads();

    const int b = blockIdx.x;
    int cnt = gcur_s[b * 16];
    if (cnt > CAP) cnt = CAP;
    const size_t base = (size_t)b * CAP;

    for (int i = tid; i < cnt; i += 1024)
        atomicAdd(&lcnt[buf[base + i] >> 17], 1);
    __syncthreads();

    int own = 0, incl = 0;
    if (tid < NPB) {
        own = lcnt[tid];
        incl = own;
#pragma unroll
        for (int off = 1; off < 64; off <<= 1) {
            int t = __shfl_up(incl, off, 64);
            if ((tid & 63) >= off) incl += t;
        }
        if ((tid & 63) == 63) wsum[tid >> 6] = incl;
    }
    __syncthreads();
    if (tid < NPB) {
        const int w = tid >> 6;
        int pfx = 0;
        if (w > 0) pfx += wsum[0];
        if (w > 1) pfx += wsum[1];
        if (w > 2) pfx += wsum[2];
        const int st = pfx + incl - own;
        sstart[tid] = st;
        scur[tid]   = st;
    }
    __syncthreads();

    for (int i = tid; i < cnt; i += 1024) {
        unsigned v = buf[base + i];
        int pos = atomicAdd(&scur[v >> 17], 1);
        slist[pos] = v & 0x1FFFF;
    }
    __syncthreads();

    const int tl = tid >> 2;
    const int q  = tid & 3;
    const int n  = b * NPB + tl;
    if (n >= NN) return;

    const int seg0 = sstart[tl];
    const int deg  = lcnt[tl];
    const int seg1 = seg0 + deg;

    float a0 = 0.f, a1 = 0.f, a2 = 0.f, a3 = 0.f;
    int i = seg0;
    for (; i + 2 <= seg1; i += 2) {
        int sA = slist[i];
        int sB = slist[i + 1];
        uint2 qa = y2[sA * 4 + q];
        uint2 qb = y2[sB * 4 + q];
        float2 fa = __half22float2(__builtin_bit_cast(__half2, qa.x));
        float2 fb = __half22float2(__builtin_bit_cast(__half2, qa.y));
        float2 fc = __half22float2(__builtin_bit_cast(__half2, qb.x));
        float2 fd = __half22float2(__builtin_bit_cast(__half2, qb.y));
        a0 += fa.x + fc.x;
        a1 += fa.y + fc.y;
        a2 += fb.x + fd.x;
        a3 += fb.y + fd.y;
    }
    if (i < seg1) {
        uint2 qa = y2[slist[i] * 4 + q];
        float2 fa = __half22float2(__builtin_bit_cast(__half2, qa.x));
        float2 fb = __half22float2(__builtin_bit_cast(__half2, qa.y));
        a0 += fa.x; a1 += fa.y; a2 += fb.x; a3 += fb.y;
    }

    const float4 sf = ((const float4*)(outv + (size_t)n * NC))[q];
    float inv = 1.0f / fmaxf((float)deg, 1.0f);
    float v0 = a0 * inv + sb[4 * q + 0] + sf.x;
    float v1 = a1 * inv + sb[4 * q + 1] + sf.y;
    float v2 = a2 * inv + sb[4 * q + 2] + sf.z;
    float v3 = a3 * inv + sb[4 * q + 3] + sf.w;

    float m = fmaxf(fmaxf(v0, v1), fmaxf(v2, v3));
    m = fmaxf(m, __shfl_xor(m, 1, 4));
    m = fmaxf(m, __shfl_xor(m, 2, 4));
    float es = expf(v0 - m) + expf(v1 - m) + expf(v2 - m) + expf(v3 - m);
    es += __shfl_xor(es, 1, 4);
    es += __shfl_xor(es, 2, 4);
    float lse = m + logf(es);

    ((float4*)(outv + (size_t)n * NC))[q] = make_float4(v0, v1, v2, v3);
    ((float4*)(logp + (size_t)n * NC))[q] =
        make_float4(v0 - lse, v1 - lse, v2 - lse, v3 - lse);
}

extern "C" void kernel_launch(void* const* d_in, const int* in_sizes, int n_in,
                              void* d_out, int out_size, void* d_ws, size_t ws_size,
                              hipStream_t stream) {
    const float* x   = (const float*)d_in[0];
    const int*   ei  = (const int*)d_in[1];
    const float* W_l = (const float*)d_in[2];
    const float* b_l = (const float*)d_in[3];
    const float* W_r = (const float*)d_in[4];

    float* logp = (float*)d_out;                    // [NN*NC]
    float* outv = (float*)d_out + (size_t)NN * NC;  // [NN*NC], self scratch

    // ws: y_l half2[NN*8] (3.2MB) | buf u32[NB*CAP] (7.2MB) | gcur_s[NB*16] (25KB)
    __half2* y_l  = (__half2*)d_ws;
    unsigned* buf = (unsigned*)(y_l + (size_t)NN * 8);
    int* gcur_s   = (int*)(buf + (size_t)NB * CAP);

    hipMemsetAsync(gcur_s, 0, (size_t)NB * 16 * sizeof(int), stream);

    fused_front<<<NBLK_PART + NBLK_LIN, 256, 0, stream>>>(
        x, W_l, W_r, ei, gcur_s, buf, y_l, outv);
    agg_kernel<<<NB, 1024, 0, stream>>>(gcur_s, buf, (const uint2*)y_l, b_l, logp, outv);
}

// Round 12
// 146.803 us; speedup vs baseline: 1.1843x; 1.1843x over previous
//
#include <hip/hip_runtime.h>
#include <hip/hip_fp16.h>
#include <math.h>

#define NN 100000
#define NE 1600000
#define FIN 50
#define NC 16
#define TILE_NODES 32

#define NPB 256                       // nodes per bucket (agg granularity)
#define NB  ((NN + NPB - 1) / NPB)    // 391 buckets
#define NPG 2048                      // nodes per group (scatter granularity)
#define NG  ((NN + NPG - 1) / NPG)    // 49 groups
#define GCAP 36864                    // slots per group region (mean 32768 + ~22 sigma)
#define NBLK_PART 256
#define EPB ((NE + NBLK_PART - 1) / NBLK_PART)   // 6250 edges / partition block
#define NBLK_LIN 1024

// ---------------------------------------------------------------------------
// Fused front-end.
// Place role (blocks [0,NBLK_PART)): scatter edges into 49 GROUP regions
// (8 buckets each). Per-(block,group) chunk = 6250/49 ~ 128 edges = 512 B =
// 8 full lines, and positions within a group advance sequentially -> each
// 64 B line completes within ~16 consecutive stores -> L2 merges to full-line
// writebacks (R8's 16-edge bucket chunks left 26 MB = 4x write amplification).
// Entry pack: src (17b) | (t & 2047) << 17  (node-in-group, 11b).
// Lin role (blocks [NBLK_PART,+NBLK_LIN)): R8-proven scalar form (VGPR 40).
// ---------------------------------------------------------------------------
__global__ __launch_bounds__(256) void fused_front(
    const float* __restrict__ x,
    const float* __restrict__ W_l,
    const float* __restrict__ W_r,
    const int* __restrict__ ei,       // [2, NE]
    int* __restrict__ gcur_s,         // [NG*16] cursors (zeroed)
    unsigned int* __restrict__ buf,   // [NG*GCAP]
    __half2* __restrict__ y_l,        // [NN*8]
    float* __restrict__ self_out)     // [NN*NC]
{
    __shared__ __align__(16) char smem[12800];
    const int tid = threadIdx.x;

    if (blockIdx.x < NBLK_PART) {
        // ---- place role ----
        int* h   = (int*)smem;        // [NG]
        int* cur = h + NG;            // [NG] running global dst index per group
        for (int i = tid; i < NG; i += 256) h[i] = 0;
        __syncthreads();
        int e0 = blockIdx.x * EPB;
        int e1 = min(e0 + EPB, NE);
        for (int e = e0 + tid; e < e1; e += 256)
            atomicAdd(&h[ei[NE + e] >> 11], 1);
        __syncthreads();
        for (int g = tid; g < NG; g += 256) {
            const int hg = h[g];
            const int base = hg ? atomicAdd(&gcur_s[g * 16], hg) : 0;
            cur[g] = g * GCAP + base;
        }
        __syncthreads();
        for (int e = e0 + tid; e < e1; e += 256) {
            int s = ei[e];
            int t = ei[NE + e];
            int g = t >> 11;
            int dst = atomicAdd(&cur[g], 1);
            if (dst < g * GCAP + GCAP)
                buf[dst] = (unsigned)s | ((unsigned)(t & 2047) << 17);
        }
    } else {
        // ---- lin role (R8 form) ----
        float* sWl = (float*)smem;            // [NC*FIN]
        float* sWr = sWl + NC * FIN;          // [NC*FIN]
        float* sx  = sWr + NC * FIN;          // [TILE_NODES*FIN]

        for (int i = tid; i < NC * FIN; i += 256) {
            sWl[i] = W_l[i];
            sWr[i] = W_r[i];
        }

        const int bidx = blockIdx.x - NBLK_PART;
        const int ntiles = (NN + TILE_NODES - 1) / TILE_NODES;
        const int ln = tid >> 3;
        const int cp = tid & 7;

        for (int tile = bidx; tile < ntiles; tile += NBLK_LIN) {
            __syncthreads();
            const int node0 = tile * TILE_NODES;
            for (int i = tid; i < TILE_NODES * FIN; i += 256) {
                int n = node0 + i / FIN;
                sx[i] = (n < NN) ? x[n * FIN + (i % FIN)] : 0.0f;
            }
            __syncthreads();

            const int n = node0 + ln;
            if (n >= NN) continue;

            const float* xr = &sx[ln * FIN];
            const float* w0 = &sWl[(2 * cp) * FIN];
            const float* w1 = w0 + FIN;
            const float* u0 = &sWr[(2 * cp) * FIN];
            const float* u1 = u0 + FIN;

            float a0 = 0.f, a1 = 0.f, r0 = 0.f, r1 = 0.f;
#pragma unroll
            for (int k = 0; k < FIN; ++k) {
                float xv = xr[k];
                a0 = fmaf(xv, w0[k], a0);
                a1 = fmaf(xv, w1[k], a1);
                r0 = fmaf(xv, u0[k], r0);
                r1 = fmaf(xv, u1[k], r1);
            }
            y_l[n * 8 + cp] = __floats2half2_rn(a0, a1);
            ((float2*)self_out)[n * 8 + cp] = make_float2(r0, r1);
        }
    }
}

// ---------------------------------------------------------------------------
// Aggregation: one 1024-thread block per BUCKET (256 nodes); reads its
// GROUP's region and filters (R9-proven pattern; 8x L2 overfetch ~ 54 MB
// device-wide ~ 2 us). In-LDS counting sort (int atomics only), 256-wide
// scan, register segment-reduce (tid = tl*4+q), fused epilogue.
// ---------------------------------------------------------------------------
__global__ __launch_bounds__(1024) void agg_kernel(
    const int* __restrict__ gcur_s,
    const unsigned int* __restrict__ buf,
    const uint2* __restrict__ y2,     // y_l as uint2[NN*4]
    const float* __restrict__ b_l,
    float* __restrict__ logp,
    float* __restrict__ outv)         // self (f32) on entry, final out on exit
{
    __shared__ unsigned slist[4608];  // 18.4 KB (bucket mean 4092 + ~8 sigma)
    __shared__ int lcnt[NPB];
    __shared__ int scur[NPB];
    __shared__ int sstart[NPB];
    __shared__ int wsum[4];
    __shared__ float sb[NC];

    const int tid = threadIdx.x;
    if (tid < NPB) lcnt[tid] = 0;
    if (tid < NC) sb[tid] = b_l[tid];
    __syncthreads();

    const int b = blockIdx.x;
    const int g = b >> 3;
    const unsigned sub = (unsigned)(b & 7);
    int cnt = gcur_s[g * 16];
    if (cnt > GCAP) cnt = GCAP;
    const size_t base = (size_t)g * GCAP;

    // pass 1: filtered per-local-node counts
    for (int i = tid; i < cnt; i += 1024) {
        unsigned tl = buf[base + i] >> 17;        // node-in-group, 0..2047
        if ((tl >> 8) == sub) atomicAdd(&lcnt[tl & 255], 1);
    }
    __syncthreads();

    // pass 2: 256-wide exclusive scan
    int own = 0, incl = 0;
    if (tid < NPB) {
        own = lcnt[tid];
        incl = own;
#pragma unroll
        for (int off = 1; off < 64; off <<= 1) {
            int t = __shfl_up(incl, off, 64);
            if ((tid & 63) >= off) incl += t;
        }
        if ((tid & 63) == 63) wsum[tid >> 6] = incl;
    }
    __syncthreads();
    if (tid < NPB) {
        const int w = tid >> 6;
        int pfx = 0;
        if (w > 0) pfx += wsum[0];
        if (w > 1) pfx += wsum[1];
        if (w > 2) pfx += wsum[2];
        const int st = pfx + incl - own;
        sstart[tid] = st;
        scur[tid]   = st;
    }
    __syncthreads();

    // pass 3: filtered scatter of src ids into sorted slots
    for (int i = tid; i < cnt; i += 1024) {
        unsigned v = buf[base + i];
        unsigned tl = v >> 17;
        if ((tl >> 8) == sub) {
            int pos = atomicAdd(&scur[tl & 255], 1);
            if (pos < 4608) slist[pos] = v & 0x1FFFF;
        }
    }
    __syncthreads();

    // pass 4: segment reduce, registers only. tid = tl*4 + q.
    const int tl = tid >> 2;
    const int q  = tid & 3;
    const int n  = b * NPB + tl;
    if (n >= NN) return;

    const int seg0 = sstart[tl];
    const int deg  = lcnt[tl];
    int seg1 = seg0 + deg;
    if (seg1 > 4608) seg1 = 4608;

    float a0 = 0.f, a1 = 0.f, a2 = 0.f, a3 = 0.f;
    int i = seg0;
    for (; i + 2 <= seg1; i += 2) {
        int sA = slist[i];
        int sB = slist[i + 1];
        uint2 qa = y2[sA * 4 + q];
        uint2 qb = y2[sB * 4 + q];
        float2 fa = __half22float2(__builtin_bit_cast(__half2, qa.x));
        float2 fb = __half22float2(__builtin_bit_cast(__half2, qa.y));
        float2 fc = __half22float2(__builtin_bit_cast(__half2, qb.x));
        float2 fd = __half22float2(__builtin_bit_cast(__half2, qb.y));
        a0 += fa.x + fc.x;
        a1 += fa.y + fc.y;
        a2 += fb.x + fd.x;
        a3 += fb.y + fd.y;
    }
    if (i < seg1) {
        uint2 qa = y2[slist[i] * 4 + q];
        float2 fa = __half22float2(__builtin_bit_cast(__half2, qa.x));
        float2 fb = __half22float2(__builtin_bit_cast(__half2, qa.y));
        a0 += fa.x; a1 += fa.y; a2 += fb.x; a3 += fb.y;
    }

    // pass 5: fused epilogue, width-4 shfl reductions
    const float4 sf = ((const float4*)(outv + (size_t)n * NC))[q];
    float inv = 1.0f / fmaxf((float)deg, 1.0f);
    float v0 = a0 * inv + sb[4 * q + 0] + sf.x;
    float v1 = a1 * inv + sb[4 * q + 1] + sf.y;
    float v2 = a2 * inv + sb[4 * q + 2] + sf.z;
    float v3 = a3 * inv + sb[4 * q + 3] + sf.w;

    float m = fmaxf(fmaxf(v0, v1), fmaxf(v2, v3));
    m = fmaxf(m, __shfl_xor(m, 1, 4));
    m = fmaxf(m, __shfl_xor(m, 2, 4));
    float es = expf(v0 - m) + expf(v1 - m) + expf(v2 - m) + expf(v3 - m);
    es += __shfl_xor(es, 1, 4);
    es += __shfl_xor(es, 2, 4);
    float lse = m + logf(es);

    ((float4*)(outv + (size_t)n * NC))[q] = make_float4(v0, v1, v2, v3);
    ((float4*)(logp + (size_t)n * NC))[q] =
        make_float4(v0 - lse, v1 - lse, v2 - lse, v3 - lse);
}

extern "C" void kernel_launch(void* const* d_in, const int* in_sizes, int n_in,
                              void* d_out, int out_size, void* d_ws, size_t ws_size,
                              hipStream_t stream) {
    const float* x   = (const float*)d_in[0];
    const int*   ei  = (const int*)d_in[1];
    const float* W_l = (const float*)d_in[2];
    const float* b_l = (const float*)d_in[3];
    const float* W_r = (const float*)d_in[4];

    float* logp = (float*)d_out;                    // [NN*NC]
    float* outv = (float*)d_out + (size_t)NN * NC;  // [NN*NC], self scratch

    // ws: y_l half2[NN*8] (3.2MB) | buf u32[NG*GCAP] (7.2MB) | gcur_s[NG*16] (3.1KB)
    __half2* y_l  = (__half2*)d_ws;
    unsigned* buf = (unsigned*)(y_l + (size_t)NN * 8);
    int* gcur_s   = (int*)(buf + (size_t)NG * GCAP);

    hipMemsetAsync(gcur_s, 0, (size_t)NG * 16 * sizeof(int), stream);

    fused_front<<<NBLK_PART + NBLK_LIN, 256, 0, stream>>>(
        x, W_l, W_r, ei, gcur_s, buf, y_l, outv);
    agg_kernel<<<NB, 1024, 0, stream>>>(gcur_s, buf, (const uint2*)y_l, b_l, logp, outv);
}

// Round 13
// 130.125 us; speedup vs baseline: 1.3361x; 1.1282x over previous
//
#include <hip/hip_runtime.h>
#include <hip/hip_fp16.h>
#include <math.h>

#define NN 100000
#define NE 1600000
#define FIN 50
#define NC 16
#define TILE_NODES 32

#define NPB 256                       // nodes per bucket (agg granularity)
#define NPG 512                       // nodes per group (scatter granularity)
#define NG  ((NN + NPG - 1) / NPG)    // 196 groups
#define GCAP 8960                     // slots per group region (mean 8163 + ~9 sigma)
#define NBLK_PART 256
#define EPB ((NE + NBLK_PART - 1) / NBLK_PART)   // 6250 edges / partition block
#define NBLK_LIN 1024
#define SLCAP 4608                    // agg slist cap (bucket mean 4081 + ~8 sigma)

// ---------------------------------------------------------------------------
// Fused front-end.
// Place role (blocks [0,NBLK_PART)): scatter edges into 196 GROUP regions
// (512 nodes each). Per-(block,group) chunk = 6250/196 ~ 32 edges = 128 B =
// 2 full lines -> lines complete quickly in L2, cutting the partial-line
// writeback traffic that bounds the scatter (R2/R6/R8: time tracks
// WRITE_SIZE at ~0.6 TB/s). Entry pack: src (17b) | (t & 511) << 17.
// Lin role (blocks [NBLK_PART,+NBLK_LIN)): R8-proven scalar form (VGPR 40).
// ---------------------------------------------------------------------------
__global__ __launch_bounds__(256) void fused_front(
    const float* __restrict__ x,
    const float* __restrict__ W_l,
    const float* __restrict__ W_r,
    const int* __restrict__ ei,       // [2, NE]
    int* __restrict__ gcur_s,         // [NG*16] cursors (zeroed)
    unsigned int* __restrict__ buf,   // [NG*GCAP]
    __half2* __restrict__ y_l,        // [NN*8]
    float* __restrict__ self_out)     // [NN*NC]
{
    __shared__ __align__(16) char smem[12800];
    const int tid = threadIdx.x;

    if (blockIdx.x < NBLK_PART) {
        // ---- place role ----
        int* h   = (int*)smem;        // [NG]
        int* cur = h + NG;            // [NG] running global dst index per group
        for (int i = tid; i < NG; i += 256) h[i] = 0;
        __syncthreads();
        int e0 = blockIdx.x * EPB;
        int e1 = min(e0 + EPB, NE);
        for (int e = e0 + tid; e < e1; e += 256)
            atomicAdd(&h[ei[NE + e] >> 9], 1);
        __syncthreads();
        for (int g = tid; g < NG; g += 256) {
            const int hg = h[g];
            const int base = hg ? atomicAdd(&gcur_s[g * 16], hg) : 0;
            cur[g] = g * GCAP + base;
        }
        __syncthreads();
        for (int e = e0 + tid; e < e1; e += 256) {
            int s = ei[e];
            int t = ei[NE + e];
            int g = t >> 9;
            int dst = atomicAdd(&cur[g], 1);
            if (dst < g * GCAP + GCAP)
                buf[dst] = (unsigned)s | ((unsigned)(t & 511) << 17);
        }
    } else {
        // ---- lin role (R8 form) ----
        float* sWl = (float*)smem;            // [NC*FIN]
        float* sWr = sWl + NC * FIN;          // [NC*FIN]
        float* sx  = sWr + NC * FIN;          // [TILE_NODES*FIN]

        for (int i = tid; i < NC * FIN; i += 256) {
            sWl[i] = W_l[i];
            sWr[i] = W_r[i];
        }

        const int bidx = blockIdx.x - NBLK_PART;
        const int ntiles = (NN + TILE_NODES - 1) / TILE_NODES;
        const int ln = tid >> 3;
        const int cp = tid & 7;

        for (int tile = bidx; tile < ntiles; tile += NBLK_LIN) {
            __syncthreads();
            const int node0 = tile * TILE_NODES;
            for (int i = tid; i < TILE_NODES * FIN; i += 256) {
                int n = node0 + i / FIN;
                sx[i] = (n < NN) ? x[n * FIN + (i % FIN)] : 0.0f;
            }
            __syncthreads();

            const int n = node0 + ln;
            if (n >= NN) continue;

            const float* xr = &sx[ln * FIN];
            const float* w0 = &sWl[(2 * cp) * FIN];
            const float* w1 = w0 + FIN;
            const float* u0 = &sWr[(2 * cp) * FIN];
            const float* u1 = u0 + FIN;

            float a0 = 0.f, a1 = 0.f, r0 = 0.f, r1 = 0.f;
#pragma unroll
            for (int k = 0; k < FIN; ++k) {
                float xv = xr[k];
                a0 = fmaf(xv, w0[k], a0);
                a1 = fmaf(xv, w1[k], a1);
                r0 = fmaf(xv, u0[k], r0);
                r1 = fmaf(xv, u1[k], r1);
            }
            y_l[n * 8 + cp] = __floats2half2_rn(a0, a1);
            ((float2*)self_out)[n * 8 + cp] = make_float2(r0, r1);
        }
    }
}

// ---------------------------------------------------------------------------
// Aggregation (R9-proven): 2 half-blocks (1024 thr) per group; half j covers
// the 256-node bucket [g*512 + j*256, +256). Filters the group list (2x
// overfetch only), in-LDS counting sort (int atomics), 256-wide scan,
// contention-free register segment-reduce (tid = tl*4+q), fused epilogue.
// ---------------------------------------------------------------------------
__global__ __launch_bounds__(1024) void agg_kernel(
    const int* __restrict__ gcur_s,
    const unsigned int* __restrict__ buf,
    const uint2* __restrict__ y2,     // y_l as uint2[NN*4]
    const float* __restrict__ b_l,
    float* __restrict__ logp,
    float* __restrict__ outv)         // self (f32) on entry, final out on exit
{
    __shared__ unsigned slist[SLCAP]; // 18.4 KB
    __shared__ int lcnt[NPB];
    __shared__ int scur[NPB];
    __shared__ int sstart[NPB];
    __shared__ int wsum[4];
    __shared__ float sb[NC];

    const int tid = threadIdx.x;
    if (tid < NPB) lcnt[tid] = 0;
    if (tid < NC) sb[tid] = b_l[tid];
    __syncthreads();

    const int g = blockIdx.x >> 1;
    const unsigned j = blockIdx.x & 1;
    int cnt = gcur_s[g * 16];
    if (cnt > GCAP) cnt = GCAP;
    const size_t base = (size_t)g * GCAP;

    // pass 1: filtered per-local-node counts
    for (int i = tid; i < cnt; i += 1024) {
        unsigned tl = buf[base + i] >> 17;        // node-in-group, 0..511
        if ((tl >> 8) == j) atomicAdd(&lcnt[tl & 255], 1);
    }
    __syncthreads();

    // pass 2: 256-wide exclusive scan
    int own = 0, incl = 0;
    if (tid < NPB) {
        own = lcnt[tid];
        incl = own;
#pragma unroll
        for (int off = 1; off < 64; off <<= 1) {
            int t = __shfl_up(incl, off, 64);
            if ((tid & 63) >= off) incl += t;
        }
        if ((tid & 63) == 63) wsum[tid >> 6] = incl;
    }
    __syncthreads();
    if (tid < NPB) {
        const int w = tid >> 6;
        int pfx = 0;
        if (w > 0) pfx += wsum[0];
        if (w > 1) pfx += wsum[1];
        if (w > 2) pfx += wsum[2];
        const int st = pfx + incl - own;
        sstart[tid] = st;
        scur[tid]   = st;
    }
    __syncthreads();

    // pass 3: filtered scatter of src ids into sorted slots
    for (int i = tid; i < cnt; i += 1024) {
        unsigned v = buf[base + i];
        unsigned tl = v >> 17;
        if ((tl >> 8) == j) {
            int pos = atomicAdd(&scur[tl & 255], 1);
            if (pos < SLCAP) slist[pos] = v & 0x1FFFF;
        }
    }
    __syncthreads();

    // pass 4: segment reduce, registers only. tid = tl*4 + q.
    const int tl = tid >> 2;
    const int q  = tid & 3;
    const int n  = (int)blockIdx.x * NPB + tl;
    if (n >= NN) return;

    const int seg0 = sstart[tl];
    const int deg  = lcnt[tl];
    int seg1 = seg0 + deg;
    if (seg1 > SLCAP) seg1 = SLCAP;

    float a0 = 0.f, a1 = 0.f, a2 = 0.f, a3 = 0.f;
    int i = seg0;
    for (; i + 2 <= seg1; i += 2) {
        int sA = slist[i];
        int sB = slist[i + 1];
        uint2 qa = y2[sA * 4 + q];
        uint2 qb = y2[sB * 4 + q];
        float2 fa = __half22float2(__builtin_bit_cast(__half2, qa.x));
        float2 fb = __half22float2(__builtin_bit_cast(__half2, qa.y));
        float2 fc = __half22float2(__builtin_bit_cast(__half2, qb.x));
        float2 fd = __half22float2(__builtin_bit_cast(__half2, qb.y));
        a0 += fa.x + fc.x;
        a1 += fa.y + fc.y;
        a2 += fb.x + fd.x;
        a3 += fb.y + fd.y;
    }
    if (i < seg1) {
        uint2 qa = y2[slist[i] * 4 + q];
        float2 fa = __half22float2(__builtin_bit_cast(__half2, qa.x));
        float2 fb = __half22float2(__builtin_bit_cast(__half2, qa.y));
        a0 += fa.x; a1 += fa.y; a2 += fb.x; a3 += fb.y;
    }

    // pass 5: fused epilogue, width-4 shfl reductions
    const float4 sf = ((const float4*)(outv + (size_t)n * NC))[q];
    float inv = 1.0f / fmaxf((float)deg, 1.0f);
    float v0 = a0 * inv + sb[4 * q + 0] + sf.x;
    float v1 = a1 * inv + sb[4 * q + 1] + sf.y;
    float v2 = a2 * inv + sb[4 * q + 2] + sf.z;
    float v3 = a3 * inv + sb[4 * q + 3] + sf.w;

    float m = fmaxf(fmaxf(v0, v1), fmaxf(v2, v3));
    m = fmaxf(m, __shfl_xor(m, 1, 4));
    m = fmaxf(m, __shfl_xor(m, 2, 4));
    float es = expf(v0 - m) + expf(v1 - m) + expf(v2 - m) + expf(v3 - m);
    es += __shfl_xor(es, 1, 4);
    es += __shfl_xor(es, 2, 4);
    float lse = m + logf(es);

    ((float4*)(outv + (size_t)n * NC))[q] = make_float4(v0, v1, v2, v3);
    ((float4*)(logp + (size_t)n * NC))[q] =
        make_float4(v0 - lse, v1 - lse, v2 - lse, v3 - lse);
}

extern "C" void kernel_launch(void* const* d_in, const int* in_sizes, int n_in,
                              void* d_out, int out_size, void* d_ws, size_t ws_size,
                              hipStream_t stream) {
    const float* x   = (const float*)d_in[0];
    const int*   ei  = (const int*)d_in[1];
    const float* W_l = (const float*)d_in[2];
    const float* b_l = (const float*)d_in[3];
    const float* W_r = (const float*)d_in[4];

    float* logp = (float*)d_out;                    // [NN*NC]
    float* outv = (float*)d_out + (size_t)NN * NC;  // [NN*NC], self scratch

    // ws: y_l half2[NN*8] (3.2MB) | buf u32[NG*GCAP] (7.0MB) | gcur_s[NG*16] (12.5KB)
    __half2* y_l  = (__half2*)d_ws;
    unsigned* buf = (unsigned*)(y_l + (size_t)NN * 8);
    int* gcur_s   = (int*)(buf + (size_t)NG * GCAP);

    hipMemsetAsync(gcur_s, 0, (size_t)NG * 16 * sizeof(int), stream);

    fused_front<<<NBLK_PART + NBLK_LIN, 256, 0, stream>>>(
        x, W_l, W_r, ei, gcur_s, buf, y_l, outv);
    agg_kernel<<<NG * 2, 1024, 0, stream>>>(gcur_s, buf, (const uint2*)y_l, b_l, logp, outv);
}